// Round 18
// baseline (1064.524 us; speedup 1.0000x reference)
//
#include <hip/hip_runtime.h>

#define N_PTS 200000
#define KC    512
#define DIM   128
#define NITER 3
#define EPS   1e-10
#define BETA  1e-3
#define PWIN  0.35f     // bf16-pruner window: f64 arg>=-32 band (0.032) + >10sigma bf16 slack
#define ACUT  -32.0     // weights below e^-32 shift centers ~1e-12 -> negligible
#define LCAND 16
#define NSUB  8         // sub-buckets per center (atomic line-contention fix, R11)
#define SUBCAP 512      // per-sub bucket capacity (total 4096/center)
#define CSTRIDE 16      // cursor padded to 64 B: one cache line per sub-cursor
#define NTILE (N_PTS / 32)   // 6250 point-tiles
#define QCAP  131072    // deferred-refine queue: measured cnt>=2 ~32-35K; R17's 32768
                        // cap silently DROPPED overflow points -> absmax 0.235. 4x margin.

typedef __attribute__((ext_vector_type(8)))  short short8;   // 8 bf16 (4 VGPR) MFMA A/B frag
typedef __attribute__((ext_vector_type(16))) float f32x16;   // 32x32 MFMA accumulator

__device__ inline unsigned short f2bf(float f) {             // f32 -> bf16 RNE
    unsigned u = __float_as_uint(f);
    unsigned r = u + 0x7FFFu + ((u >> 16) & 1u);
    return (unsigned short)(r >> 16);
}
// order-preserving f32 <-> u32 (monotone bijection; exact)
__device__ inline unsigned ordu(float f) {
    unsigned u = __float_as_uint(f);
    return (u & 0x80000000u) ? ~u : (u | 0x80000000u);
}
__device__ inline float unordu(unsigned u) {
    return __uint_as_float((u & 0x80000000u) ? (u ^ 0x80000000u) : ~u);
}

// A/B fragment layout for mfma_f32_32x32x16_bf16: entity row/col = lane&31,
// k = (lane>>5)*8 + i, i=0..7. Packed flat: [(tile*8 + kb)*64 + lane] as short8.

// ---------------- k_packx: X -> bf16 A-fragments (once; x is iteration-invariant) ----------------
__global__ void k_packx(const float* __restrict__ x, short8* __restrict__ Xf) {
    int pt = blockIdx.x;                       // 6250 point-tiles of 32
    int tid = threadIdx.x;                     // 256
    int lane = tid & 63, g = tid >> 6;
    int row = pt * 32 + (lane & 31);
    int koff = (lane >> 5) * 8;
    #pragma unroll
    for (int kk = 0; kk < 2; ++kk) {
        int kb = g * 2 + kk;
        short8 v;
        #pragma unroll
        for (int i = 0; i < 8; ++i)
            ((unsigned short*)&v)[i] = f2bf(x[(size_t)row * DIM + kb * 16 + koff + i]);
        Xf[((size_t)pt * 8 + kb) * 64 + lane] = v;
    }
}

// ---------------- k_init: Cf64, C-fragments, csq, zero num/den/cursors/queue ----------------
__global__ void k_init(const float* __restrict__ cin, double* __restrict__ Cf64,
                       unsigned short* __restrict__ Cfrag, double* __restrict__ csqd,
                       float* __restrict__ csqf, double* __restrict__ num,
                       double* __restrict__ den, unsigned* __restrict__ cursor,
                       unsigned* __restrict__ qcnt) {
    int k = blockIdx.x, d = threadIdx.x;       // 512 blocks x 128 threads
    float v = cin[k * DIM + d];
    double c = (double)v;
    Cf64[(size_t)k * DIM + d] = c;
    num[(size_t)k * DIM + d] = 0.0;
    if (d < NSUB) cursor[((size_t)k * NSUB + d) * CSTRIDE] = 0u;
    if (k == 0 && d == 0) qcnt[0] = 0u;
    int ct = k >> 5, kb = d >> 4, j = d & 15;
    int lane = (k & 31) + 32 * (j >> 3);
    Cfrag[(((size_t)ct * 8 + kb) * 64 + lane) * 8 + (j & 7)] = f2bf(v);
    double p = c * c;
    #pragma unroll
    for (int m = 1; m < 64; m <<= 1) p += __shfl_xor(p, m);
    __shared__ double ps[2];
    if ((d & 63) == 0) ps[d >> 6] = p;
    __syncthreads();
    if (d == 0) {
        double s = ps[0] + ps[1];
        csqd[k] = s; csqf[k] = (float)s;
        den[k] = 0.0;
    }
}

// ---------------- k_dense: MFMA prune + LDS-atomicMin row-min + fastpath + queue ----------------
// 512 threads = 8 waves; one 32-pt tile/block; wave wv covers col-tiles {wv*2,wv*2+1}.
// vs R14: (1) 5-stage shfl butterfly + merge replaced by DS-pipe atomicMin on
// ordered-uint floats; (2) cnt>=2 refine deferred to k_refine. Min is bit-exact.
__launch_bounds__(512)
__global__ void k_dense(const short8* __restrict__ Xf, const short8* __restrict__ Cfrag,
                        const float* __restrict__ csqf, unsigned* __restrict__ cursor,
                        unsigned* __restrict__ entries_n, double* __restrict__ entries_w,
                        unsigned* __restrict__ qcnt, unsigned* __restrict__ qn,
                        unsigned short* __restrict__ qcl) {
    __shared__ unsigned       rowmin_u[32];
    __shared__ int            ccnt[32];
    __shared__ unsigned short clist[32][LCAND];

    const int tid = threadIdx.x;
    const int wv = tid >> 6, lane = tid & 63;
    const int blk = blockIdx.x;                // 6250 blocks, one tile each
    const int sub = blk & (NSUB - 1);
    const int h = lane >> 5;
    const int ct0 = wv * 2, ct1 = wv * 2 + 1;

    if (tid < 32) { rowmin_u[tid] = 0xFFFFFFFFu; ccnt[tid] = 0; }
    __syncthreads();                           // B1: init visible before atomics

    // A-fragments: this tile's 32 points (8 waves load the same -> L1 hits)
    short8 a[8];
    #pragma unroll
    for (int kb = 0; kb < 8; ++kb)
        a[kb] = Xf[((size_t)blk * 8 + kb) * 64 + lane];

    f32x16 acc0, acc1;
    #pragma unroll
    for (int r = 0; r < 16; ++r) { acc0[r] = 0.0f; acc1[r] = 0.0f; }
    #pragma unroll
    for (int kb = 0; kb < 8; ++kb) {
        short8 b0 = Cfrag[((size_t)ct0 * 8 + kb) * 64 + lane];
        short8 b1 = Cfrag[((size_t)ct1 * 8 + kb) * 64 + lane];
        acc0 = __builtin_amdgcn_mfma_f32_32x32x16_bf16(a[kb], b0, acc0, 0, 0, 0);
        acc1 = __builtin_amdgcn_mfma_f32_32x32x16_bf16(a[kb], b1, acc1, 0, 0, 0);
    }
    const float cq0 = csqf[ct0 * 32 + (lane & 31)];
    const float cq1 = csqf[ct1 * 32 + (lane & 31)];
    float dd[2][16];
    #pragma unroll
    for (int r = 0; r < 16; ++r) {
        dd[0][r] = cq0 - 2.0f * acc0[r];
        dd[1][r] = cq1 - 2.0f * acc1[r];
    }

    // row-min via DS-pipe atomicMin on ordered uints (bit-exact min; no butterfly)
    // (C/D layout: col=lane&31, row=(r&3)+8*(r>>2)+4*(lane>>5))
    #pragma unroll
    for (int r = 0; r < 16; ++r) {
        int row = (r & 3) + 8 * (r >> 2) + 4 * h;
        atomicMin(&rowmin_u[row], ordu(fminf(dd[0][r], dd[1][r])));
    }
    __syncthreads();                           // B2: all mins landed

    // candidate collection (full global min known BEFORE any collection)
    #pragma unroll
    for (int tt = 0; tt < 2; ++tt) {
        int ct = wv * 2 + tt;
        #pragma unroll
        for (int r = 0; r < 16; ++r) {
            int row = (r & 3) + 8 * (r >> 2) + 4 * h;
            float thr = unordu(rowmin_u[row]) + PWIN;
            if (dd[tt][r] < thr) {
                int idx = atomicAdd(&ccnt[row], 1);
                if (idx < LCAND)
                    clist[row][idx] = (unsigned short)(ct * 32 + (lane & 31));
            }
        }
    }
    __syncthreads();                           // B3: ccnt/clist complete

    // cnt==1 fast path, PARALLEL: lanes 0..3 of each wave handle 4 points.
    // Sole candidate IS the argmin; all others sit >= ~e^-250 below in f64
    // => weight is bit-exactly 1.0. No dot, no softmax, no x read.
    if (lane < 4) {
        int p = wv * 4 + lane;
        if (ccnt[p] == 1) {
            int k = clist[p][0];
            size_t base = (size_t)k * NSUB + sub;
            unsigned pos = atomicAdd(&cursor[base * CSTRIDE], 1u);
            if (pos < SUBCAP) {
                entries_n[base * SUBCAP + pos] = (unsigned)(blk * 32 + p);
                entries_w[base * SUBCAP + pos] = 1.0;
            }
        }
    }
    // cnt>=2: push to global refine queue (~16-25% of points; QCAP has 4x margin)
    if (tid < 32 && ccnt[tid] > 1) {
        int cnt = ccnt[tid]; if (cnt > LCAND) cnt = LCAND;
        unsigned qi = atomicAdd(qcnt, 1u);
        if (qi < QCAP) {
            qn[qi] = (unsigned)(blk * 32 + tid) | ((unsigned)cnt << 24);
            for (int c = 0; c < cnt; ++c)
                qcl[(size_t)qi * LCAND + c] = clist[tid][c];
        }
    }
}

// ---------------- k_refine: exact f64 softmax for queued cnt>=2 points ----------------
// grid-stride, one wave per queued point; identical math to R14's refine phase.
__global__ void k_refine(const float* __restrict__ x, const double* __restrict__ Cf64,
                         const double* __restrict__ csqd, const unsigned* __restrict__ qcnt,
                         const unsigned* __restrict__ qn, const unsigned short* __restrict__ qcl,
                         unsigned* __restrict__ cursor,
                         unsigned* __restrict__ entries_n, double* __restrict__ entries_w) {
    int lane = threadIdx.x & 63;
    unsigned gw = (blockIdx.x * blockDim.x + threadIdx.x) >> 6;
    unsigned nw = (gridDim.x * blockDim.x) >> 6;
    unsigned total = qcnt[0]; if (total > QCAP) total = QCAP;

    for (unsigned q = gw; q < total; q += nw) {
        unsigned rec = qn[q];
        int n = (int)(rec & 0xFFFFFFu);
        int cnt = (int)(rec >> 24);
        int sub = (n >> 5) & (NSUB - 1);       // == tile & 7

        // exact f64 refine + softmax (||x||^2 dropped: common mode in softmax)
        double xa = (double)x[(size_t)n * DIM + lane];
        double xb = (double)x[(size_t)n * DIM + 64 + lane];

        double myd = 1e300; int myk = -1;
        for (int c = 0; c < cnt; ++c) {
            int k = (int)qcl[(size_t)q * LCAND + c];
            double pr = xa * Cf64[(size_t)k * DIM + lane]
                      + xb * Cf64[(size_t)k * DIM + 64 + lane];
            #pragma unroll
            for (int m = 1; m < 64; m <<= 1) pr += __shfl_xor(pr, m);
            double dist = csqd[k] - 2.0 * pr;
            if (lane == c) { myd = dist; myk = k; }
        }
        double md = myd;
        #pragma unroll
        for (int m = 1; m < 64; m <<= 1) md = fmin(md, __shfl_xor(md, m));
        double zm = -md / BETA;
        double arg = (myk >= 0) ? (-myd / BETA - zm) : -1e300;
        double e = (myk >= 0) ? exp(arg) : 0.0;
        double esum = e;
        #pragma unroll
        for (int m = 1; m < 64; m <<= 1) esum += __shfl_xor(esum, m);

        if (myk >= 0 && arg >= ACUT) {
            double wgt = e / esum;             // once, on the candidate lane only
            size_t base = (size_t)myk * NSUB + sub;
            unsigned pos = atomicAdd(&cursor[base * CSTRIDE], 1u);
            if (pos < SUBCAP) {
                entries_n[base * SUBCAP + pos] = (unsigned)n;
                entries_w[base * SUBCAP + pos] = wgt;
            }
        }
    }
}

// ---------------- k_reduce: gather per-center entries, partial f64 sums ----------------
// 2048 blocks = 4 partials per center (2 sub-buckets each); 128 threads (one per dim)
__global__ void k_reduce(const float* __restrict__ x, const unsigned* __restrict__ cursor,
                         const unsigned* __restrict__ entries_n,
                         const double* __restrict__ entries_w,
                         double* __restrict__ num, double* __restrict__ den) {
    int b = blockIdx.x;
    int k = b >> 2, part = b & 3;
    int d = threadIdx.x;

    double a0 = 0.0, a1 = 0.0, a2 = 0.0, a3 = 0.0, ws = 0.0;
    #pragma unroll
    for (int s = 0; s < 2; ++s) {
        int sub = part * 2 + s;
        size_t base = (size_t)k * NSUB + sub;
        unsigned len = cursor[base * CSTRIDE]; if (len > SUBCAP) len = SUBCAP;
        const unsigned* en = entries_n + base * SUBCAP;
        const double*   ew = entries_w + base * SUBCAP;
        unsigned e = 0;
        for (; e + 4 <= len; e += 4) {
            unsigned n0 = en[e], n1 = en[e + 1], n2 = en[e + 2], n3 = en[e + 3];
            double w0 = ew[e], w1 = ew[e + 1], w2 = ew[e + 2], w3 = ew[e + 3];
            float f0 = x[(size_t)n0 * DIM + d];
            float f1 = x[(size_t)n1 * DIM + d];
            float f2 = x[(size_t)n2 * DIM + d];
            float f3 = x[(size_t)n3 * DIM + d];
            a0 += w0 * (double)f0; a1 += w1 * (double)f1;
            a2 += w2 * (double)f2; a3 += w3 * (double)f3;
            ws += ((w0 + w1) + (w2 + w3));
        }
        for (; e < len; ++e) {
            unsigned n0 = en[e]; double w0 = ew[e];
            a0 += w0 * (double)x[(size_t)n0 * DIM + d];
            ws += w0;
        }
    }
    double acc = (a0 + a1) + (a2 + a3);
    atomicAdd(&num[(size_t)k * DIM + d], acc);
    if (d == 0) atomicAdd(&den[k], ws);
}

// ---------------- k_update: centers = num/(den+EPS); refresh; zero state ----------------
__global__ void k_update(double* __restrict__ num, double* __restrict__ den,
                         double* __restrict__ Cf64, unsigned short* __restrict__ Cfrag,
                         double* __restrict__ csqd, float* __restrict__ csqf,
                         unsigned* __restrict__ cursor, unsigned* __restrict__ qcnt,
                         float* __restrict__ out, int last) {
    int k = blockIdx.x, d = threadIdx.x;       // 512 blocks x 128 threads
    double nv = num[(size_t)k * DIM + d];
    double dv = den[k] + EPS;
    double c = nv / dv;
    Cf64[(size_t)k * DIM + d] = c;
    num[(size_t)k * DIM + d] = 0.0;
    if (d < NSUB) cursor[((size_t)k * NSUB + d) * CSTRIDE] = 0u;
    if (k == 0 && d == 0) qcnt[0] = 0u;
    if (last) out[k * DIM + d] = (float)c;
    int ct = k >> 5, kb = d >> 4, j = d & 15;
    int lane = (k & 31) + 32 * (j >> 3);
    Cfrag[(((size_t)ct * 8 + kb) * 64 + lane) * 8 + (j & 7)] = f2bf((float)c);
    double p = c * c;
    #pragma unroll
    for (int m = 1; m < 64; m <<= 1) p += __shfl_xor(p, m);
    __shared__ double ps[2];
    if ((d & 63) == 0) ps[d >> 6] = p;
    __syncthreads();
    if (d == 0) {
        double s = ps[0] + ps[1];
        csqd[k] = s; csqf[k] = (float)s;
        den[k] = 0.0;
    }
}

extern "C" void kernel_launch(void* const* d_in, const int* in_sizes, int n_in,
                              void* d_out, int out_size, void* d_ws, size_t ws_size,
                              hipStream_t stream) {
    const float* x   = (const float*)d_in[0];
    const float* cin = (const float*)d_in[1];
    float* out = (float*)d_out;

    char* w = (char*)d_ws;
    size_t off = 0;
    auto alloc = [&](size_t bytes) -> void* {
        void* p = w + off;
        off = (off + bytes + 255) & ~(size_t)255;
        return p;
    };
    double*         Cf64   = (double*)alloc((size_t)KC * DIM * 8);          // 512 KB
    unsigned short* Cfrag  = (unsigned short*)alloc((size_t)KC * DIM * 2);  // 128 KB
    double*         csqd   = (double*)alloc((size_t)KC * 8);
    float*          csqf   = (float*)alloc((size_t)KC * 4);
    double*         num    = (double*)alloc((size_t)KC * DIM * 8);          // 512 KB
    double*         den    = (double*)alloc((size_t)KC * 8);
    unsigned*       cursor = (unsigned*)alloc((size_t)KC * NSUB * CSTRIDE * 4);   // 256 KB
    unsigned*       entries_n = (unsigned*)alloc((size_t)KC * NSUB * SUBCAP * 4); // 8.4 MB
    double*         entries_w = (double*)alloc((size_t)KC * NSUB * SUBCAP * 8);   // 16.8 MB
    unsigned*       qcnt   = (unsigned*)alloc(256);
    unsigned*       qn     = (unsigned*)alloc((size_t)QCAP * 4);            // 512 KB
    unsigned short* qcl    = (unsigned short*)alloc((size_t)QCAP * LCAND * 2); // 4 MB
    short8*         Xf     = (short8*)alloc((size_t)N_PTS * DIM * 2);       // 51.2 MB
    (void)ws_size; (void)in_sizes; (void)n_in; (void)out_size;

    hipLaunchKernelGGL(k_init, dim3(KC), dim3(DIM), 0, stream,
                       cin, Cf64, Cfrag, csqd, csqf, num, den, cursor, qcnt);
    hipLaunchKernelGGL(k_packx, dim3(NTILE), dim3(256), 0, stream, x, Xf);

    for (int it = 0; it < NITER; ++it) {
        hipLaunchKernelGGL(k_dense, dim3(NTILE), dim3(512), 0, stream,
                           Xf, (const short8*)Cfrag, csqf,
                           cursor, entries_n, entries_w, qcnt, qn, qcl);
        hipLaunchKernelGGL(k_refine, dim3(512), dim3(256), 0, stream,
                           x, Cf64, csqd, qcnt, qn, qcl,
                           cursor, entries_n, entries_w);
        hipLaunchKernelGGL(k_reduce, dim3(KC * 4), dim3(DIM), 0, stream,
                           x, cursor, entries_n, entries_w, num, den);
        hipLaunchKernelGGL(k_update, dim3(KC), dim3(DIM), 0, stream,
                           num, den, Cf64, Cfrag, csqd, csqf, cursor, qcnt, out,
                           (it == NITER - 1) ? 1 : 0);
    }
}

// Round 19
// 603.516 us; speedup vs baseline: 1.7639x; 1.7639x over previous
//
#include <hip/hip_runtime.h>

#define N_PTS 200000
#define KC    512
#define DIM   128
#define NITER 3
#define EPS   1e-10
#define BETA  1e-3
#define PWIN  0.35f     // bf16-pruner window: f64 arg>=-32 band (0.032) + >10sigma bf16 slack
#define ACUT  -32.0     // weights below e^-32 shift centers ~1e-12 -> negligible
#define LCAND 16
#define NSUB  8         // sub-buckets per center (atomic line-contention fix, R11)
#define SUBCAP 512      // per-sub bucket capacity (total 4096/center)
#define CSTRIDE 16      // cursor padded to 64 B: one cache line per sub-cursor
#define NTILE (N_PTS / 32)   // 6250 point-tiles
#define QCAP  131072    // deferred-refine queue (R17's 32768 overflowed -> dropped points)

typedef __attribute__((ext_vector_type(8)))  short short8;   // 8 bf16 (4 VGPR) MFMA A/B frag
typedef __attribute__((ext_vector_type(16))) float f32x16;   // 32x32 MFMA accumulator

__device__ inline unsigned short f2bf(float f) {             // f32 -> bf16 RNE
    unsigned u = __float_as_uint(f);
    unsigned r = u + 0x7FFFu + ((u >> 16) & 1u);
    return (unsigned short)(r >> 16);
}

// A/B fragment layout for mfma_f32_32x32x16_bf16: entity row/col = lane&31,
// k = (lane>>5)*8 + i, i=0..7. Packed flat: [(tile*8 + kb)*64 + lane] as short8.

// ---------------- k_packx: X -> bf16 A-fragments (once; x is iteration-invariant) ----------------
__global__ void k_packx(const float* __restrict__ x, short8* __restrict__ Xf) {
    int pt = blockIdx.x;                       // 6250 point-tiles of 32
    int tid = threadIdx.x;                     // 256
    int lane = tid & 63, g = tid >> 6;
    int row = pt * 32 + (lane & 31);
    int koff = (lane >> 5) * 8;
    #pragma unroll
    for (int kk = 0; kk < 2; ++kk) {
        int kb = g * 2 + kk;
        short8 v;
        #pragma unroll
        for (int i = 0; i < 8; ++i)
            ((unsigned short*)&v)[i] = f2bf(x[(size_t)row * DIM + kb * 16 + koff + i]);
        Xf[((size_t)pt * 8 + kb) * 64 + lane] = v;
    }
}

// ---------------- k_init: Cf64, C-fragments, csq, zero num/den/cursors/queue ----------------
__global__ void k_init(const float* __restrict__ cin, double* __restrict__ Cf64,
                       unsigned short* __restrict__ Cfrag, double* __restrict__ csqd,
                       float* __restrict__ csqf, double* __restrict__ num,
                       double* __restrict__ den, unsigned* __restrict__ cursor,
                       unsigned* __restrict__ qcnt) {
    int k = blockIdx.x, d = threadIdx.x;       // 512 blocks x 128 threads
    float v = cin[k * DIM + d];
    double c = (double)v;
    Cf64[(size_t)k * DIM + d] = c;
    num[(size_t)k * DIM + d] = 0.0;
    if (d < NSUB) cursor[((size_t)k * NSUB + d) * CSTRIDE] = 0u;
    if (k == 0 && d == 0) qcnt[0] = 0u;
    int ct = k >> 5, kb = d >> 4, j = d & 15;
    int lane = (k & 31) + 32 * (j >> 3);
    Cfrag[(((size_t)ct * 8 + kb) * 64 + lane) * 8 + (j & 7)] = f2bf(v);
    double p = c * c;
    #pragma unroll
    for (int m = 1; m < 64; m <<= 1) p += __shfl_xor(p, m);
    __shared__ double ps[2];
    if ((d & 63) == 0) ps[d >> 6] = p;
    __syncthreads();
    if (d == 0) {
        double s = ps[0] + ps[1];
        csqd[k] = s; csqf[k] = (float)s;
        den[k] = 0.0;
    }
}

// ---------------- k_dense: MFMA prune + butterfly row-min + fastpath + queue ----------------
// 512 threads = 8 waves; one 32-pt tile/block; wave wv covers col-tiles {wv*2,wv*2+1}.
// R14's shuffle-butterfly min (R18's LDS atomicMin serialized 256-deep on the DS pipe:
// 4.96e7 bank conflicts) + R18's deferred cnt>=2 refine (no straggler tail, no x reads).
__launch_bounds__(512)
__global__ void k_dense(const short8* __restrict__ Xf, const short8* __restrict__ Cfrag,
                        const float* __restrict__ csqf, unsigned* __restrict__ cursor,
                        unsigned* __restrict__ entries_n, double* __restrict__ entries_w,
                        unsigned* __restrict__ qcnt, unsigned* __restrict__ qn,
                        unsigned short* __restrict__ qcl) {
    __shared__ float          rowmin_w[8][32];
    __shared__ float          rowmin_s[32];
    __shared__ int            ccnt[32];
    __shared__ unsigned short clist[32][LCAND];

    const int tid = threadIdx.x;
    const int wv = tid >> 6, lane = tid & 63;
    const int blk = blockIdx.x;                // 6250 blocks, one tile each
    const int sub = blk & (NSUB - 1);
    const int h = lane >> 5;
    const int ct0 = wv * 2, ct1 = wv * 2 + 1;

    // A-fragments: this tile's 32 points (8 waves load the same -> L1 hits)
    short8 a[8];
    #pragma unroll
    for (int kb = 0; kb < 8; ++kb)
        a[kb] = Xf[((size_t)blk * 8 + kb) * 64 + lane];

    f32x16 acc0, acc1;
    #pragma unroll
    for (int r = 0; r < 16; ++r) { acc0[r] = 0.0f; acc1[r] = 0.0f; }
    #pragma unroll
    for (int kb = 0; kb < 8; ++kb) {
        short8 b0 = Cfrag[((size_t)ct0 * 8 + kb) * 64 + lane];
        short8 b1 = Cfrag[((size_t)ct1 * 8 + kb) * 64 + lane];
        acc0 = __builtin_amdgcn_mfma_f32_32x32x16_bf16(a[kb], b0, acc0, 0, 0, 0);
        acc1 = __builtin_amdgcn_mfma_f32_32x32x16_bf16(a[kb], b1, acc1, 0, 0, 0);
    }
    const float cq0 = csqf[ct0 * 32 + (lane & 31)];
    const float cq1 = csqf[ct1 * 32 + (lane & 31)];
    float dd[2][16];
    #pragma unroll
    for (int r = 0; r < 16; ++r) {
        dd[0][r] = cq0 - 2.0f * acc0[r];
        dd[1][r] = cq1 - 2.0f * acc1[r];
    }

    // per-row min over this wave's 64 cols, 5-stage shuffle butterfly (conflict-free)
    // (C/D layout: col=lane&31, row=(r&3)+8*(r>>2)+4*(lane>>5))
    float mt[16];
    #pragma unroll
    for (int r = 0; r < 16; ++r) {
        float m = fminf(dd[0][r], dd[1][r]);
        #pragma unroll
        for (int s = 16; s >= 1; s >>= 1) m = fminf(m, __shfl_xor(m, s));
        mt[r] = m;
    }
    if ((lane & 31) == 0) {
        #pragma unroll
        for (int r = 0; r < 16; ++r)
            rowmin_w[wv][(r & 3) + 8 * (r >> 2) + 4 * h] = mt[r];
    }
    __syncthreads();                           // B1: per-wave mins landed
    if (tid < 32) {
        float m = rowmin_w[0][tid];
        #pragma unroll
        for (int w8 = 1; w8 < 8; ++w8) m = fminf(m, rowmin_w[w8][tid]);
        rowmin_s[tid] = m;
        ccnt[tid] = 0;
    }
    __syncthreads();                           // B2: global min + ccnt init visible

    // candidate collection (full global min known BEFORE any collection)
    #pragma unroll
    for (int tt = 0; tt < 2; ++tt) {
        int ct = wv * 2 + tt;
        #pragma unroll
        for (int r = 0; r < 16; ++r) {
            int row = (r & 3) + 8 * (r >> 2) + 4 * h;
            if (dd[tt][r] - rowmin_s[row] < PWIN) {
                int idx = atomicAdd(&ccnt[row], 1);
                if (idx < LCAND)
                    clist[row][idx] = (unsigned short)(ct * 32 + (lane & 31));
            }
        }
    }
    __syncthreads();                           // B3: ccnt/clist complete

    // cnt==1 fast path, PARALLEL: lanes 0..3 of each wave handle 4 points.
    // Sole candidate IS the argmin; all others sit >= ~e^-250 below in f64
    // => weight is bit-exactly 1.0. No dot, no softmax, no x read.
    if (lane < 4) {
        int p = wv * 4 + lane;
        if (ccnt[p] == 1) {
            int k = clist[p][0];
            size_t base = (size_t)k * NSUB + sub;
            unsigned pos = atomicAdd(&cursor[base * CSTRIDE], 1u);
            if (pos < SUBCAP) {
                entries_n[base * SUBCAP + pos] = (unsigned)(blk * 32 + p);
                entries_w[base * SUBCAP + pos] = 1.0;
            }
        }
    }
    // cnt>=2: push to global refine queue (~16-25% of points; QCAP has 4x margin)
    if (tid < 32 && ccnt[tid] > 1) {
        int cnt = ccnt[tid]; if (cnt > LCAND) cnt = LCAND;
        unsigned qi = atomicAdd(qcnt, 1u);
        if (qi < QCAP) {
            qn[qi] = (unsigned)(blk * 32 + tid) | ((unsigned)cnt << 24);
            for (int c = 0; c < cnt; ++c)
                qcl[(size_t)qi * LCAND + c] = clist[tid][c];
        }
    }
}

// ---------------- k_refine: exact f64 softmax for queued cnt>=2 points ----------------
// grid-stride, one wave per queued point; identical math to R14's refine phase.
__global__ void k_refine(const float* __restrict__ x, const double* __restrict__ Cf64,
                         const double* __restrict__ csqd, const unsigned* __restrict__ qcnt,
                         const unsigned* __restrict__ qn, const unsigned short* __restrict__ qcl,
                         unsigned* __restrict__ cursor,
                         unsigned* __restrict__ entries_n, double* __restrict__ entries_w) {
    int lane = threadIdx.x & 63;
    unsigned gw = (blockIdx.x * blockDim.x + threadIdx.x) >> 6;
    unsigned nw = (gridDim.x * blockDim.x) >> 6;
    unsigned total = qcnt[0]; if (total > QCAP) total = QCAP;

    for (unsigned q = gw; q < total; q += nw) {
        unsigned rec = qn[q];
        int n = (int)(rec & 0xFFFFFFu);
        int cnt = (int)(rec >> 24);
        int sub = (n >> 5) & (NSUB - 1);       // == tile & 7

        // exact f64 refine + softmax (||x||^2 dropped: common mode in softmax)
        double xa = (double)x[(size_t)n * DIM + lane];
        double xb = (double)x[(size_t)n * DIM + 64 + lane];

        double myd = 1e300; int myk = -1;
        for (int c = 0; c < cnt; ++c) {
            int k = (int)qcl[(size_t)q * LCAND + c];
            double pr = xa * Cf64[(size_t)k * DIM + lane]
                      + xb * Cf64[(size_t)k * DIM + 64 + lane];
            #pragma unroll
            for (int m = 1; m < 64; m <<= 1) pr += __shfl_xor(pr, m);
            double dist = csqd[k] - 2.0 * pr;
            if (lane == c) { myd = dist; myk = k; }
        }
        double md = myd;
        #pragma unroll
        for (int m = 1; m < 64; m <<= 1) md = fmin(md, __shfl_xor(md, m));
        double zm = -md / BETA;
        double arg = (myk >= 0) ? (-myd / BETA - zm) : -1e300;
        double e = (myk >= 0) ? exp(arg) : 0.0;
        double esum = e;
        #pragma unroll
        for (int m = 1; m < 64; m <<= 1) esum += __shfl_xor(esum, m);

        if (myk >= 0 && arg >= ACUT) {
            double wgt = e / esum;             // once, on the candidate lane only
            size_t base = (size_t)myk * NSUB + sub;
            unsigned pos = atomicAdd(&cursor[base * CSTRIDE], 1u);
            if (pos < SUBCAP) {
                entries_n[base * SUBCAP + pos] = (unsigned)n;
                entries_w[base * SUBCAP + pos] = wgt;
            }
        }
    }
}

// ---------------- k_reduce: gather per-center entries, partial f64 sums ----------------
// 2048 blocks = 4 partials per center (2 sub-buckets each); 128 threads (one per dim)
__global__ void k_reduce(const float* __restrict__ x, const unsigned* __restrict__ cursor,
                         const unsigned* __restrict__ entries_n,
                         const double* __restrict__ entries_w,
                         double* __restrict__ num, double* __restrict__ den) {
    int b = blockIdx.x;
    int k = b >> 2, part = b & 3;
    int d = threadIdx.x;

    double a0 = 0.0, a1 = 0.0, a2 = 0.0, a3 = 0.0, ws = 0.0;
    #pragma unroll
    for (int s = 0; s < 2; ++s) {
        int sub = part * 2 + s;
        size_t base = (size_t)k * NSUB + sub;
        unsigned len = cursor[base * CSTRIDE]; if (len > SUBCAP) len = SUBCAP;
        const unsigned* en = entries_n + base * SUBCAP;
        const double*   ew = entries_w + base * SUBCAP;
        unsigned e = 0;
        for (; e + 4 <= len; e += 4) {
            unsigned n0 = en[e], n1 = en[e + 1], n2 = en[e + 2], n3 = en[e + 3];
            double w0 = ew[e], w1 = ew[e + 1], w2 = ew[e + 2], w3 = ew[e + 3];
            float f0 = x[(size_t)n0 * DIM + d];
            float f1 = x[(size_t)n1 * DIM + d];
            float f2 = x[(size_t)n2 * DIM + d];
            float f3 = x[(size_t)n3 * DIM + d];
            a0 += w0 * (double)f0; a1 += w1 * (double)f1;
            a2 += w2 * (double)f2; a3 += w3 * (double)f3;
            ws += ((w0 + w1) + (w2 + w3));
        }
        for (; e < len; ++e) {
            unsigned n0 = en[e]; double w0 = ew[e];
            a0 += w0 * (double)x[(size_t)n0 * DIM + d];
            ws += w0;
        }
    }
    double acc = (a0 + a1) + (a2 + a3);
    atomicAdd(&num[(size_t)k * DIM + d], acc);
    if (d == 0) atomicAdd(&den[k], ws);
}

// ---------------- k_update: centers = num/(den+EPS); refresh; zero state ----------------
__global__ void k_update(double* __restrict__ num, double* __restrict__ den,
                         double* __restrict__ Cf64, unsigned short* __restrict__ Cfrag,
                         double* __restrict__ csqd, float* __restrict__ csqf,
                         unsigned* __restrict__ cursor, unsigned* __restrict__ qcnt,
                         float* __restrict__ out, int last) {
    int k = blockIdx.x, d = threadIdx.x;       // 512 blocks x 128 threads
    double nv = num[(size_t)k * DIM + d];
    double dv = den[k] + EPS;
    double c = nv / dv;
    Cf64[(size_t)k * DIM + d] = c;
    num[(size_t)k * DIM + d] = 0.0;
    if (d < NSUB) cursor[((size_t)k * NSUB + d) * CSTRIDE] = 0u;
    if (k == 0 && d == 0) qcnt[0] = 0u;
    if (last) out[k * DIM + d] = (float)c;
    int ct = k >> 5, kb = d >> 4, j = d & 15;
    int lane = (k & 31) + 32 * (j >> 3);
    Cfrag[(((size_t)ct * 8 + kb) * 64 + lane) * 8 + (j & 7)] = f2bf((float)c);
    double p = c * c;
    #pragma unroll
    for (int m = 1; m < 64; m <<= 1) p += __shfl_xor(p, m);
    __shared__ double ps[2];
    if ((d & 63) == 0) ps[d >> 6] = p;
    __syncthreads();
    if (d == 0) {
        double s = ps[0] + ps[1];
        csqd[k] = s; csqf[k] = (float)s;
        den[k] = 0.0;
    }
}

extern "C" void kernel_launch(void* const* d_in, const int* in_sizes, int n_in,
                              void* d_out, int out_size, void* d_ws, size_t ws_size,
                              hipStream_t stream) {
    const float* x   = (const float*)d_in[0];
    const float* cin = (const float*)d_in[1];
    float* out = (float*)d_out;

    char* w = (char*)d_ws;
    size_t off = 0;
    auto alloc = [&](size_t bytes) -> void* {
        void* p = w + off;
        off = (off + bytes + 255) & ~(size_t)255;
        return p;
    };
    double*         Cf64   = (double*)alloc((size_t)KC * DIM * 8);          // 512 KB
    unsigned short* Cfrag  = (unsigned short*)alloc((size_t)KC * DIM * 2);  // 128 KB
    double*         csqd   = (double*)alloc((size_t)KC * 8);
    float*          csqf   = (float*)alloc((size_t)KC * 4);
    double*         num    = (double*)alloc((size_t)KC * DIM * 8);          // 512 KB
    double*         den    = (double*)alloc((size_t)KC * 8);
    unsigned*       cursor = (unsigned*)alloc((size_t)KC * NSUB * CSTRIDE * 4);   // 256 KB
    unsigned*       entries_n = (unsigned*)alloc((size_t)KC * NSUB * SUBCAP * 4); // 8.4 MB
    double*         entries_w = (double*)alloc((size_t)KC * NSUB * SUBCAP * 8);   // 16.8 MB
    unsigned*       qcnt   = (unsigned*)alloc(256);
    unsigned*       qn     = (unsigned*)alloc((size_t)QCAP * 4);            // 512 KB
    unsigned short* qcl    = (unsigned short*)alloc((size_t)QCAP * LCAND * 2); // 4 MB
    short8*         Xf     = (short8*)alloc((size_t)N_PTS * DIM * 2);       // 51.2 MB
    (void)ws_size; (void)in_sizes; (void)n_in; (void)out_size;

    hipLaunchKernelGGL(k_init, dim3(KC), dim3(DIM), 0, stream,
                       cin, Cf64, Cfrag, csqd, csqf, num, den, cursor, qcnt);
    hipLaunchKernelGGL(k_packx, dim3(NTILE), dim3(256), 0, stream, x, Xf);

    for (int it = 0; it < NITER; ++it) {
        hipLaunchKernelGGL(k_dense, dim3(NTILE), dim3(512), 0, stream,
                           Xf, (const short8*)Cfrag, csqf,
                           cursor, entries_n, entries_w, qcnt, qn, qcl);
        hipLaunchKernelGGL(k_refine, dim3(512), dim3(256), 0, stream,
                           x, Cf64, csqd, qcnt, qn, qcl,
                           cursor, entries_n, entries_w);
        hipLaunchKernelGGL(k_reduce, dim3(KC * 4), dim3(DIM), 0, stream,
                           x, cursor, entries_n, entries_w, num, den);
        hipLaunchKernelGGL(k_update, dim3(KC), dim3(DIM), 0, stream,
                           num, den, Cf64, Cfrag, csqd, csqf, cursor, qcnt, out,
                           (it == NITER - 1) ? 1 : 0);
    }
}

// Round 20
// 552.640 us; speedup vs baseline: 1.9263x; 1.0921x over previous
//
#include <hip/hip_runtime.h>

#define N_PTS 200000
#define KC    512
#define DIM   128
#define NITER 3
#define EPS   1e-10
#define BETA  1e-3
#define PWIN  0.35f     // bf16-pruner window: f64 arg>=-32 band (0.032) + >10sigma bf16 slack
#define ACUT  -32.0     // weights below e^-32 shift centers ~1e-12 -> negligible
#define LCAND 16
#define NSUB  8         // sub-buckets per center (atomic line-contention fix, R11)
#define SUBCAP 512      // per-sub bucket capacity (total 4096/center)
#define CSTRIDE 16      // cursor padded to 64 B: one cache line per sub-cursor
#define NTILE (N_PTS / 32)   // 6250 point-tiles
#define QCAP  131072    // deferred-refine queue (R17's 32768 overflowed -> dropped points)

typedef __attribute__((ext_vector_type(8)))  short short8;   // 8 bf16 (4 VGPR) MFMA A/B frag
typedef __attribute__((ext_vector_type(16))) float f32x16;   // 32x32 MFMA accumulator

__device__ inline unsigned short f2bf(float f) {             // f32 -> bf16 RNE
    unsigned u = __float_as_uint(f);
    unsigned r = u + 0x7FFFu + ((u >> 16) & 1u);
    return (unsigned short)(r >> 16);
}

// A/B fragment layout for mfma_f32_32x32x16_bf16: entity row/col = lane&31,
// k = (lane>>5)*8 + i, i=0..7. Packed flat: [(tile*8 + kb)*64 + lane] as short8.

// ---------------- k_packx: X -> bf16 A-fragments (once; x is iteration-invariant) ----------------
__global__ void k_packx(const float* __restrict__ x, short8* __restrict__ Xf) {
    int pt = blockIdx.x;                       // 6250 point-tiles of 32
    int tid = threadIdx.x;                     // 256
    int lane = tid & 63, g = tid >> 6;
    int row = pt * 32 + (lane & 31);
    int koff = (lane >> 5) * 8;
    #pragma unroll
    for (int kk = 0; kk < 2; ++kk) {
        int kb = g * 2 + kk;
        short8 v;
        #pragma unroll
        for (int i = 0; i < 8; ++i)
            ((unsigned short*)&v)[i] = f2bf(x[(size_t)row * DIM + kb * 16 + koff + i]);
        Xf[((size_t)pt * 8 + kb) * 64 + lane] = v;
    }
}

// ---------------- k_init: Cf64, C-fragments, csq, zero num/den/cursors/queue ----------------
__global__ void k_init(const float* __restrict__ cin, double* __restrict__ Cf64,
                       unsigned short* __restrict__ Cfrag, double* __restrict__ csqd,
                       float* __restrict__ csqf, double* __restrict__ num,
                       double* __restrict__ den, unsigned* __restrict__ cursor,
                       unsigned* __restrict__ qcnt) {
    int k = blockIdx.x, d = threadIdx.x;       // 512 blocks x 128 threads
    float v = cin[k * DIM + d];
    double c = (double)v;
    Cf64[(size_t)k * DIM + d] = c;
    num[(size_t)k * DIM + d] = 0.0;
    if (d < NSUB) cursor[((size_t)k * NSUB + d) * CSTRIDE] = 0u;
    if (k == 0 && d == 0) qcnt[0] = 0u;
    int ct = k >> 5, kb = d >> 4, j = d & 15;
    int lane = (k & 31) + 32 * (j >> 3);
    Cfrag[(((size_t)ct * 8 + kb) * 64 + lane) * 8 + (j & 7)] = f2bf(v);
    double p = c * c;
    #pragma unroll
    for (int m = 1; m < 64; m <<= 1) p += __shfl_xor(p, m);
    __shared__ double ps[2];
    if ((d & 63) == 0) ps[d >> 6] = p;
    __syncthreads();
    if (d == 0) {
        double s = ps[0] + ps[1];
        csqd[k] = s; csqf[k] = (float)s;
        den[k] = 0.0;
    }
}

// ---------------- k_dense: MFMA prune + butterfly row-min + fastpath + queue ----------------
// 512 threads = 8 waves; one 32-pt tile/block; wave wv covers col-tiles {wv*2,wv*2+1}.
__launch_bounds__(512)
__global__ void k_dense(const short8* __restrict__ Xf, const short8* __restrict__ Cfrag,
                        const float* __restrict__ csqf, unsigned* __restrict__ cursor,
                        unsigned* __restrict__ entries_n, double* __restrict__ entries_w,
                        unsigned* __restrict__ qcnt, unsigned* __restrict__ qn,
                        unsigned short* __restrict__ qcl) {
    __shared__ float          rowmin_w[8][32];
    __shared__ float          rowmin_s[32];
    __shared__ int            ccnt[32];
    __shared__ unsigned short clist[32][LCAND];

    const int tid = threadIdx.x;
    const int wv = tid >> 6, lane = tid & 63;
    const int blk = blockIdx.x;                // 6250 blocks, one tile each
    const int sub = blk & (NSUB - 1);
    const int h = lane >> 5;
    const int ct0 = wv * 2, ct1 = wv * 2 + 1;

    // A-fragments: this tile's 32 points (8 waves load the same -> L1 hits)
    short8 a[8];
    #pragma unroll
    for (int kb = 0; kb < 8; ++kb)
        a[kb] = Xf[((size_t)blk * 8 + kb) * 64 + lane];

    f32x16 acc0, acc1;
    #pragma unroll
    for (int r = 0; r < 16; ++r) { acc0[r] = 0.0f; acc1[r] = 0.0f; }
    #pragma unroll
    for (int kb = 0; kb < 8; ++kb) {
        short8 b0 = Cfrag[((size_t)ct0 * 8 + kb) * 64 + lane];
        short8 b1 = Cfrag[((size_t)ct1 * 8 + kb) * 64 + lane];
        acc0 = __builtin_amdgcn_mfma_f32_32x32x16_bf16(a[kb], b0, acc0, 0, 0, 0);
        acc1 = __builtin_amdgcn_mfma_f32_32x32x16_bf16(a[kb], b1, acc1, 0, 0, 0);
    }
    const float cq0 = csqf[ct0 * 32 + (lane & 31)];
    const float cq1 = csqf[ct1 * 32 + (lane & 31)];
    float dd[2][16];
    #pragma unroll
    for (int r = 0; r < 16; ++r) {
        dd[0][r] = cq0 - 2.0f * acc0[r];
        dd[1][r] = cq1 - 2.0f * acc1[r];
    }

    // per-row min over this wave's 64 cols, 5-stage shuffle butterfly (conflict-free)
    // (C/D layout: col=lane&31, row=(r&3)+8*(r>>2)+4*(lane>>5))
    float mt[16];
    #pragma unroll
    for (int r = 0; r < 16; ++r) {
        float m = fminf(dd[0][r], dd[1][r]);
        #pragma unroll
        for (int s = 16; s >= 1; s >>= 1) m = fminf(m, __shfl_xor(m, s));
        mt[r] = m;
    }
    if ((lane & 31) == 0) {
        #pragma unroll
        for (int r = 0; r < 16; ++r)
            rowmin_w[wv][(r & 3) + 8 * (r >> 2) + 4 * h] = mt[r];
    }
    __syncthreads();                           // B1: per-wave mins landed
    if (tid < 32) {
        float m = rowmin_w[0][tid];
        #pragma unroll
        for (int w8 = 1; w8 < 8; ++w8) m = fminf(m, rowmin_w[w8][tid]);
        rowmin_s[tid] = m;
        ccnt[tid] = 0;
    }
    __syncthreads();                           // B2: global min + ccnt init visible

    // candidate collection (full global min known BEFORE any collection)
    #pragma unroll
    for (int tt = 0; tt < 2; ++tt) {
        int ct = wv * 2 + tt;
        #pragma unroll
        for (int r = 0; r < 16; ++r) {
            int row = (r & 3) + 8 * (r >> 2) + 4 * h;
            if (dd[tt][r] - rowmin_s[row] < PWIN) {
                int idx = atomicAdd(&ccnt[row], 1);
                if (idx < LCAND)
                    clist[row][idx] = (unsigned short)(ct * 32 + (lane & 31));
            }
        }
    }
    __syncthreads();                           // B3: ccnt/clist complete

    // cnt==1 fast path, PARALLEL: lanes 0..3 of each wave handle 4 points.
    // Sole candidate IS the argmin; all others sit >= ~e^-250 below in f64
    // => weight is bit-exactly 1.0. No dot, no softmax, no x read.
    if (lane < 4) {
        int p = wv * 4 + lane;
        if (ccnt[p] == 1) {
            int k = clist[p][0];
            size_t base = (size_t)k * NSUB + sub;
            unsigned pos = atomicAdd(&cursor[base * CSTRIDE], 1u);
            if (pos < SUBCAP) {
                entries_n[base * SUBCAP + pos] = (unsigned)(blk * 32 + p);
                entries_w[base * SUBCAP + pos] = 1.0;
            }
        }
    }
    // cnt>=2: push to global refine queue (~16-25% of points; QCAP has 4x margin)
    if (tid < 32 && ccnt[tid] > 1) {
        int cnt = ccnt[tid]; if (cnt > LCAND) cnt = LCAND;
        unsigned qi = atomicAdd(qcnt, 1u);
        if (qi < QCAP) {
            qn[qi] = (unsigned)(blk * 32 + tid) | ((unsigned)cnt << 24);
            for (int c = 0; c < cnt; ++c)
                qcl[(size_t)qi * LCAND + c] = clist[tid][c];
        }
    }
}

// ---------------- refine helper: all CN candidates batched (one butterfly pass) ----------------
// Loads for all candidates issue together (one latency round); the 6-stage f64
// butterfly reduces all CN partials per stage (independent shuffles pipeline);
// afterwards EVERY lane holds every candidate's dist -> min/esum are register
// chains (no extra butterflies). pr summation order identical to R19 (bit-exact).
template<int CN>
__device__ inline void do_refine(const float* __restrict__ x, const double* __restrict__ Cf64,
                                 const double* __restrict__ csqd,
                                 const unsigned short* __restrict__ cl, int n, int cnt,
                                 int lane, int sub, unsigned* __restrict__ cursor,
                                 unsigned* __restrict__ entries_n,
                                 double* __restrict__ entries_w) {
    double xa = (double)x[(size_t)n * DIM + lane];
    double xb = (double)x[(size_t)n * DIM + 64 + lane];
    int    ks[CN];
    double part[CN];
    #pragma unroll
    for (int c = 0; c < CN; ++c) {
        int k = (c < cnt) ? (int)cl[c] : (int)cl[0];
        ks[c] = k;
        part[c] = xa * Cf64[(size_t)k * DIM + lane] + xb * Cf64[(size_t)k * DIM + 64 + lane];
    }
    #pragma unroll
    for (int m = 1; m < 64; m <<= 1) {
        #pragma unroll
        for (int c = 0; c < CN; ++c) part[c] += __shfl_xor(part[c], m);
    }
    double dist[CN];
    #pragma unroll
    for (int c = 0; c < CN; ++c) dist[c] = csqd[ks[c]] - 2.0 * part[c];
    double md = 1e300;
    #pragma unroll
    for (int c = 0; c < CN; ++c) if (c < cnt) md = fmin(md, dist[c]);
    double zm = -md / BETA;
    double esum = 0.0;
    double my_ar = -1e300; int my_k = -1;
    #pragma unroll
    for (int c = 0; c < CN; ++c) {
        if (c < cnt) {
            double ar = -dist[c] / BETA - zm;
            esum += exp(ar);
            if (lane == c) { my_ar = ar; my_k = ks[c]; }   // static-index lane select
        }
    }
    if (my_k >= 0 && my_ar >= ACUT) {
        double wgt = exp(my_ar) / esum;
        size_t base = (size_t)my_k * NSUB + sub;
        unsigned pos = atomicAdd(&cursor[base * CSTRIDE], 1u);
        if (pos < SUBCAP) {
            entries_n[base * SUBCAP + pos] = (unsigned)n;
            entries_w[base * SUBCAP + pos] = wgt;
        }
    }
}

// ---------------- k_refine: exact f64 softmax for queued cnt>=2 points ----------------
// grid-stride, one wave per queued point; cnt-class dispatch for static indexing.
__global__ void k_refine(const float* __restrict__ x, const double* __restrict__ Cf64,
                         const double* __restrict__ csqd, const unsigned* __restrict__ qcnt,
                         const unsigned* __restrict__ qn, const unsigned short* __restrict__ qcl,
                         unsigned* __restrict__ cursor,
                         unsigned* __restrict__ entries_n, double* __restrict__ entries_w) {
    int lane = threadIdx.x & 63;
    unsigned gw = (blockIdx.x * blockDim.x + threadIdx.x) >> 6;
    unsigned nw = (gridDim.x * blockDim.x) >> 6;
    unsigned total = qcnt[0]; if (total > QCAP) total = QCAP;

    for (unsigned q = gw; q < total; q += nw) {
        unsigned rec = qn[q];
        int n = (int)(rec & 0xFFFFFFu);
        int cnt = (int)(rec >> 24);
        int sub = (n >> 5) & (NSUB - 1);       // == tile & 7
        const unsigned short* cl = qcl + (size_t)q * LCAND;

        if (cnt == 2) {
            do_refine<2>(x, Cf64, csqd, cl, n, cnt, lane, sub, cursor, entries_n, entries_w);
        } else if (cnt <= 4) {
            do_refine<4>(x, Cf64, csqd, cl, n, cnt, lane, sub, cursor, entries_n, entries_w);
        } else if (cnt <= 8) {
            do_refine<8>(x, Cf64, csqd, cl, n, cnt, lane, sub, cursor, entries_n, entries_w);
        } else {
            // rare fallback (cnt 9..16): R19's serial-candidate path
            double xa = (double)x[(size_t)n * DIM + lane];
            double xb = (double)x[(size_t)n * DIM + 64 + lane];
            double myd = 1e300; int myk = -1;
            for (int c = 0; c < cnt; ++c) {
                int k = (int)cl[c];
                double pr = xa * Cf64[(size_t)k * DIM + lane]
                          + xb * Cf64[(size_t)k * DIM + 64 + lane];
                #pragma unroll
                for (int m = 1; m < 64; m <<= 1) pr += __shfl_xor(pr, m);
                double dist = csqd[k] - 2.0 * pr;
                if (lane == c) { myd = dist; myk = k; }
            }
            double md = myd;
            #pragma unroll
            for (int m = 1; m < 64; m <<= 1) md = fmin(md, __shfl_xor(md, m));
            double zm = -md / BETA;
            double arg = (myk >= 0) ? (-myd / BETA - zm) : -1e300;
            double e = (myk >= 0) ? exp(arg) : 0.0;
            double esum = e;
            #pragma unroll
            for (int m = 1; m < 64; m <<= 1) esum += __shfl_xor(esum, m);
            if (myk >= 0 && arg >= ACUT) {
                double wgt = e / esum;
                size_t base = (size_t)myk * NSUB + sub;
                unsigned pos = atomicAdd(&cursor[base * CSTRIDE], 1u);
                if (pos < SUBCAP) {
                    entries_n[base * SUBCAP + pos] = (unsigned)n;
                    entries_w[base * SUBCAP + pos] = wgt;
                }
            }
        }
    }
}

// ---------------- k_reduce: gather per-center entries, partial f64 sums ----------------
// 2048 blocks = 4 partials per center (2 sub-buckets each); 128 threads (one per dim)
__global__ void k_reduce(const float* __restrict__ x, const unsigned* __restrict__ cursor,
                         const unsigned* __restrict__ entries_n,
                         const double* __restrict__ entries_w,
                         double* __restrict__ num, double* __restrict__ den) {
    int b = blockIdx.x;
    int k = b >> 2, part = b & 3;
    int d = threadIdx.x;

    double a0 = 0.0, a1 = 0.0, a2 = 0.0, a3 = 0.0, ws = 0.0;
    #pragma unroll
    for (int s = 0; s < 2; ++s) {
        int sub = part * 2 + s;
        size_t base = (size_t)k * NSUB + sub;
        unsigned len = cursor[base * CSTRIDE]; if (len > SUBCAP) len = SUBCAP;
        const unsigned* en = entries_n + base * SUBCAP;
        const double*   ew = entries_w + base * SUBCAP;
        unsigned e = 0;
        for (; e + 4 <= len; e += 4) {
            unsigned n0 = en[e], n1 = en[e + 1], n2 = en[e + 2], n3 = en[e + 3];
            double w0 = ew[e], w1 = ew[e + 1], w2 = ew[e + 2], w3 = ew[e + 3];
            float f0 = x[(size_t)n0 * DIM + d];
            float f1 = x[(size_t)n1 * DIM + d];
            float f2 = x[(size_t)n2 * DIM + d];
            float f3 = x[(size_t)n3 * DIM + d];
            a0 += w0 * (double)f0; a1 += w1 * (double)f1;
            a2 += w2 * (double)f2; a3 += w3 * (double)f3;
            ws += ((w0 + w1) + (w2 + w3));
        }
        for (; e < len; ++e) {
            unsigned n0 = en[e]; double w0 = ew[e];
            a0 += w0 * (double)x[(size_t)n0 * DIM + d];
            ws += w0;
        }
    }
    double acc = (a0 + a1) + (a2 + a3);
    atomicAdd(&num[(size_t)k * DIM + d], acc);
    if (d == 0) atomicAdd(&den[k], ws);
}

// ---------------- k_update: centers = num/(den+EPS); refresh; zero state ----------------
__global__ void k_update(double* __restrict__ num, double* __restrict__ den,
                         double* __restrict__ Cf64, unsigned short* __restrict__ Cfrag,
                         double* __restrict__ csqd, float* __restrict__ csqf,
                         unsigned* __restrict__ cursor, unsigned* __restrict__ qcnt,
                         float* __restrict__ out, int last) {
    int k = blockIdx.x, d = threadIdx.x;       // 512 blocks x 128 threads
    double nv = num[(size_t)k * DIM + d];
    double dv = den[k] + EPS;
    double c = nv / dv;
    Cf64[(size_t)k * DIM + d] = c;
    num[(size_t)k * DIM + d] = 0.0;
    if (d < NSUB) cursor[((size_t)k * NSUB + d) * CSTRIDE] = 0u;
    if (k == 0 && d == 0) qcnt[0] = 0u;
    if (last) out[k * DIM + d] = (float)c;
    int ct = k >> 5, kb = d >> 4, j = d & 15;
    int lane = (k & 31) + 32 * (j >> 3);
    Cfrag[(((size_t)ct * 8 + kb) * 64 + lane) * 8 + (j & 7)] = f2bf((float)c);
    double p = c * c;
    #pragma unroll
    for (int m = 1; m < 64; m <<= 1) p += __shfl_xor(p, m);
    __shared__ double ps[2];
    if ((d & 63) == 0) ps[d >> 6] = p;
    __syncthreads();
    if (d == 0) {
        double s = ps[0] + ps[1];
        csqd[k] = s; csqf[k] = (float)s;
        den[k] = 0.0;
    }
}

extern "C" void kernel_launch(void* const* d_in, const int* in_sizes, int n_in,
                              void* d_out, int out_size, void* d_ws, size_t ws_size,
                              hipStream_t stream) {
    const float* x   = (const float*)d_in[0];
    const float* cin = (const float*)d_in[1];
    float* out = (float*)d_out;

    char* w = (char*)d_ws;
    size_t off = 0;
    auto alloc = [&](size_t bytes) -> void* {
        void* p = w + off;
        off = (off + bytes + 255) & ~(size_t)255;
        return p;
    };
    double*         Cf64   = (double*)alloc((size_t)KC * DIM * 8);          // 512 KB
    unsigned short* Cfrag  = (unsigned short*)alloc((size_t)KC * DIM * 2);  // 128 KB
    double*         csqd   = (double*)alloc((size_t)KC * 8);
    float*          csqf   = (float*)alloc((size_t)KC * 4);
    double*         num    = (double*)alloc((size_t)KC * DIM * 8);          // 512 KB
    double*         den    = (double*)alloc((size_t)KC * 8);
    unsigned*       cursor = (unsigned*)alloc((size_t)KC * NSUB * CSTRIDE * 4);   // 256 KB
    unsigned*       entries_n = (unsigned*)alloc((size_t)KC * NSUB * SUBCAP * 4); // 8.4 MB
    double*         entries_w = (double*)alloc((size_t)KC * NSUB * SUBCAP * 8);   // 16.8 MB
    unsigned*       qcnt   = (unsigned*)alloc(256);
    unsigned*       qn     = (unsigned*)alloc((size_t)QCAP * 4);            // 512 KB
    unsigned short* qcl    = (unsigned short*)alloc((size_t)QCAP * LCAND * 2); // 4 MB
    short8*         Xf     = (short8*)alloc((size_t)N_PTS * DIM * 2);       // 51.2 MB
    (void)ws_size; (void)in_sizes; (void)n_in; (void)out_size;

    hipLaunchKernelGGL(k_init, dim3(KC), dim3(DIM), 0, stream,
                       cin, Cf64, Cfrag, csqd, csqf, num, den, cursor, qcnt);
    hipLaunchKernelGGL(k_packx, dim3(NTILE), dim3(256), 0, stream, x, Xf);

    for (int it = 0; it < NITER; ++it) {
        hipLaunchKernelGGL(k_dense, dim3(NTILE), dim3(512), 0, stream,
                           Xf, (const short8*)Cfrag, csqf,
                           cursor, entries_n, entries_w, qcnt, qn, qcl);
        hipLaunchKernelGGL(k_refine, dim3(512), dim3(256), 0, stream,
                           x, Cf64, csqd, qcnt, qn, qcl,
                           cursor, entries_n, entries_w);
        hipLaunchKernelGGL(k_reduce, dim3(KC * 4), dim3(DIM), 0, stream,
                           x, cursor, entries_n, entries_w, num, den);
        hipLaunchKernelGGL(k_update, dim3(KC), dim3(DIM), 0, stream,
                           num, den, Cf64, Cfrag, csqd, csqf, cursor, qcnt, out,
                           (it == NITER - 1) ? 1 : 0);
    }
}

// Round 21
// 500.349 us; speedup vs baseline: 2.1276x; 1.1045x over previous
//
#include <hip/hip_runtime.h>

#define N_PTS 200000
#define KC    512
#define DIM   128
#define NITER 3
#define EPS   1e-10
#define BETA  1e-3
#define PWIN  0.35f     // bf16-pruner window: f64 arg>=-32 band (0.032) + >10sigma bf16 slack
#define ACUT  -32.0     // weights below e^-32 shift centers ~1e-12 -> negligible
#define LCAND 16
#define NSUB  8         // sub-buckets per center (atomic line-contention fix, R11)
#define SUBCAP 512      // per-sub bucket capacity (total 4096/center)
#define CSTRIDE 16      // cursor padded to 64 B: one cache line per sub-cursor
#define NTILE (N_PTS / 32)   // 6250 point-tiles
#define QCAP  131072    // deferred-refine queue (R17's 32768 overflowed -> dropped points)

typedef __attribute__((ext_vector_type(8)))  short short8;   // 8 bf16 (4 VGPR) MFMA A/B frag
typedef __attribute__((ext_vector_type(16))) float f32x16;   // 32x32 MFMA accumulator

__device__ inline unsigned short f2bf(float f) {             // f32 -> bf16 RNE
    unsigned u = __float_as_uint(f);
    unsigned r = u + 0x7FFFu + ((u >> 16) & 1u);
    return (unsigned short)(r >> 16);
}

// A/B fragment layout for mfma_f32_32x32x16_bf16: entity row/col = lane&31,
// k = (lane>>5)*8 + i, i=0..7. Packed flat: [(tile*8 + kb)*64 + lane] as short8.

// ---------------- k_packx: X -> bf16 A-fragments (once; x is iteration-invariant) ----------------
__global__ void k_packx(const float* __restrict__ x, short8* __restrict__ Xf) {
    int pt = blockIdx.x;                       // 6250 point-tiles of 32
    int tid = threadIdx.x;                     // 256
    int lane = tid & 63, g = tid >> 6;
    int row = pt * 32 + (lane & 31);
    int koff = (lane >> 5) * 8;
    #pragma unroll
    for (int kk = 0; kk < 2; ++kk) {
        int kb = g * 2 + kk;
        short8 v;
        #pragma unroll
        for (int i = 0; i < 8; ++i)
            ((unsigned short*)&v)[i] = f2bf(x[(size_t)row * DIM + kb * 16 + koff + i]);
        Xf[((size_t)pt * 8 + kb) * 64 + lane] = v;
    }
}

// ---------------- k_init: Cf64, C-fragments, csq, zero num/den/cursors/queue ----------------
__global__ void k_init(const float* __restrict__ cin, double* __restrict__ Cf64,
                       unsigned short* __restrict__ Cfrag, double* __restrict__ csqd,
                       float* __restrict__ csqf, double* __restrict__ num,
                       double* __restrict__ den, unsigned* __restrict__ cursor,
                       unsigned* __restrict__ qcnt) {
    int k = blockIdx.x, d = threadIdx.x;       // 512 blocks x 128 threads
    float v = cin[k * DIM + d];
    double c = (double)v;
    Cf64[(size_t)k * DIM + d] = c;
    num[(size_t)k * DIM + d] = 0.0;
    if (d < NSUB) cursor[((size_t)k * NSUB + d) * CSTRIDE] = 0u;
    if (k == 0 && d == 0) qcnt[0] = 0u;
    int ct = k >> 5, kb = d >> 4, j = d & 15;
    int lane = (k & 31) + 32 * (j >> 3);
    Cfrag[(((size_t)ct * 8 + kb) * 64 + lane) * 8 + (j & 7)] = f2bf(v);
    double p = c * c;
    #pragma unroll
    for (int m = 1; m < 64; m <<= 1) p += __shfl_xor(p, m);
    __shared__ double ps[2];
    if ((d & 63) == 0) ps[d >> 6] = p;
    __syncthreads();
    if (d == 0) {
        double s = ps[0] + ps[1];
        csqd[k] = s; csqf[k] = (float)s;
        den[k] = 0.0;
    }
}

// ---------------- k_dense: MFMA prune + butterfly row-min + fastpath + queue ----------------
// 512 threads = 8 waves; one 32-pt tile/block; wave wv covers col-tiles {wv*2,wv*2+1}.
__launch_bounds__(512)
__global__ void k_dense(const short8* __restrict__ Xf, const short8* __restrict__ Cfrag,
                        const float* __restrict__ csqf, unsigned* __restrict__ cursor,
                        unsigned* __restrict__ entries_n, double* __restrict__ entries_w,
                        unsigned* __restrict__ qcnt, unsigned* __restrict__ qn,
                        unsigned short* __restrict__ qcl) {
    __shared__ float          rowmin_w[8][32];
    __shared__ float          rowmin_s[32];
    __shared__ int            ccnt[32];
    __shared__ unsigned short clist[32][LCAND];

    const int tid = threadIdx.x;
    const int wv = tid >> 6, lane = tid & 63;
    const int blk = blockIdx.x;                // 6250 blocks, one tile each
    const int sub = blk & (NSUB - 1);
    const int h = lane >> 5;
    const int ct0 = wv * 2, ct1 = wv * 2 + 1;

    // A-fragments: this tile's 32 points (8 waves load the same -> L1 hits)
    short8 a[8];
    #pragma unroll
    for (int kb = 0; kb < 8; ++kb)
        a[kb] = Xf[((size_t)blk * 8 + kb) * 64 + lane];

    f32x16 acc0, acc1;
    #pragma unroll
    for (int r = 0; r < 16; ++r) { acc0[r] = 0.0f; acc1[r] = 0.0f; }
    #pragma unroll
    for (int kb = 0; kb < 8; ++kb) {
        short8 b0 = Cfrag[((size_t)ct0 * 8 + kb) * 64 + lane];
        short8 b1 = Cfrag[((size_t)ct1 * 8 + kb) * 64 + lane];
        acc0 = __builtin_amdgcn_mfma_f32_32x32x16_bf16(a[kb], b0, acc0, 0, 0, 0);
        acc1 = __builtin_amdgcn_mfma_f32_32x32x16_bf16(a[kb], b1, acc1, 0, 0, 0);
    }
    const float cq0 = csqf[ct0 * 32 + (lane & 31)];
    const float cq1 = csqf[ct1 * 32 + (lane & 31)];
    float dd[2][16];
    #pragma unroll
    for (int r = 0; r < 16; ++r) {
        dd[0][r] = cq0 - 2.0f * acc0[r];
        dd[1][r] = cq1 - 2.0f * acc1[r];
    }

    // per-row min over this wave's 64 cols, 5-stage shuffle butterfly (conflict-free)
    // (C/D layout: col=lane&31, row=(r&3)+8*(r>>2)+4*(lane>>5))
    float mt[16];
    #pragma unroll
    for (int r = 0; r < 16; ++r) {
        float m = fminf(dd[0][r], dd[1][r]);
        #pragma unroll
        for (int s = 16; s >= 1; s >>= 1) m = fminf(m, __shfl_xor(m, s));
        mt[r] = m;
    }
    if ((lane & 31) == 0) {
        #pragma unroll
        for (int r = 0; r < 16; ++r)
            rowmin_w[wv][(r & 3) + 8 * (r >> 2) + 4 * h] = mt[r];
    }
    __syncthreads();                           // B1: per-wave mins landed
    if (tid < 32) {
        float m = rowmin_w[0][tid];
        #pragma unroll
        for (int w8 = 1; w8 < 8; ++w8) m = fminf(m, rowmin_w[w8][tid]);
        rowmin_s[tid] = m;
        ccnt[tid] = 0;
    }
    __syncthreads();                           // B2: global min + ccnt init visible

    // candidate collection (full global min known BEFORE any collection)
    #pragma unroll
    for (int tt = 0; tt < 2; ++tt) {
        int ct = wv * 2 + tt;
        #pragma unroll
        for (int r = 0; r < 16; ++r) {
            int row = (r & 3) + 8 * (r >> 2) + 4 * h;
            if (dd[tt][r] - rowmin_s[row] < PWIN) {
                int idx = atomicAdd(&ccnt[row], 1);
                if (idx < LCAND)
                    clist[row][idx] = (unsigned short)(ct * 32 + (lane & 31));
            }
        }
    }
    __syncthreads();                           // B3: ccnt/clist complete

    // cnt==1 fast path, PARALLEL: lanes 0..3 of each wave handle 4 points.
    // Sole candidate IS the argmin; all others sit >= ~e^-250 below in f64
    // => weight is bit-exactly 1.0. No dot, no softmax, no x read.
    if (lane < 4) {
        int p = wv * 4 + lane;
        if (ccnt[p] == 1) {
            int k = clist[p][0];
            size_t base = (size_t)k * NSUB + sub;
            unsigned pos = atomicAdd(&cursor[base * CSTRIDE], 1u);
            if (pos < SUBCAP) {
                entries_n[base * SUBCAP + pos] = (unsigned)(blk * 32 + p);
                entries_w[base * SUBCAP + pos] = 1.0;
            }
        }
    }
    // cnt>=2: push to global refine queue (~16-25% of points; QCAP has 4x margin)
    if (tid < 32 && ccnt[tid] > 1) {
        int cnt = ccnt[tid]; if (cnt > LCAND) cnt = LCAND;
        unsigned qi = atomicAdd(qcnt, 1u);
        if (qi < QCAP) {
            qn[qi] = (unsigned)(blk * 32 + tid) | ((unsigned)cnt << 24);
            for (int c = 0; c < cnt; ++c)
                qcl[(size_t)qi * LCAND + c] = clist[tid][c];
        }
    }
}

// ---------------- refine helper: all CN candidates batched (one butterfly pass) ----------------
template<int CN>
__device__ inline void do_refine(const float* __restrict__ x, const double* __restrict__ Cf64,
                                 const double* __restrict__ csqd,
                                 const unsigned short* __restrict__ cl, int n, int cnt,
                                 int lane, int sub, unsigned* __restrict__ cursor,
                                 unsigned* __restrict__ entries_n,
                                 double* __restrict__ entries_w) {
    double xa = (double)x[(size_t)n * DIM + lane];
    double xb = (double)x[(size_t)n * DIM + 64 + lane];
    int    ks[CN];
    double part[CN];
    #pragma unroll
    for (int c = 0; c < CN; ++c) {
        int k = (c < cnt) ? (int)cl[c] : (int)cl[0];
        ks[c] = k;
        part[c] = xa * Cf64[(size_t)k * DIM + lane] + xb * Cf64[(size_t)k * DIM + 64 + lane];
    }
    #pragma unroll
    for (int m = 1; m < 64; m <<= 1) {
        #pragma unroll
        for (int c = 0; c < CN; ++c) part[c] += __shfl_xor(part[c], m);
    }
    double dist[CN];
    #pragma unroll
    for (int c = 0; c < CN; ++c) dist[c] = csqd[ks[c]] - 2.0 * part[c];
    double md = 1e300;
    #pragma unroll
    for (int c = 0; c < CN; ++c) if (c < cnt) md = fmin(md, dist[c]);
    double zm = -md / BETA;
    double esum = 0.0;
    double my_ar = -1e300; int my_k = -1;
    #pragma unroll
    for (int c = 0; c < CN; ++c) {
        if (c < cnt) {
            double ar = -dist[c] / BETA - zm;
            esum += exp(ar);
            if (lane == c) { my_ar = ar; my_k = ks[c]; }   // static-index lane select
        }
    }
    if (my_k >= 0 && my_ar >= ACUT) {
        double wgt = exp(my_ar) / esum;
        size_t base = (size_t)my_k * NSUB + sub;
        unsigned pos = atomicAdd(&cursor[base * CSTRIDE], 1u);
        if (pos < SUBCAP) {
            entries_n[base * SUBCAP + pos] = (unsigned)n;
            entries_w[base * SUBCAP + pos] = wgt;
        }
    }
}

// ---------------- k_refine: exact f64 softmax for queued cnt>=2 points ----------------
// grid-stride, one wave per queued point. R21: 2048 blocks (was 512) -> 32 waves/CU.
// R20 profile: 8 waves/CU, 17% occupancy, 97% stall on ~16K-cyc/entry latency chains;
// issue floor and 32-way-overlapped latency both converge at ~30 us/iter.
__global__ void k_refine(const float* __restrict__ x, const double* __restrict__ Cf64,
                         const double* __restrict__ csqd, const unsigned* __restrict__ qcnt,
                         const unsigned* __restrict__ qn, const unsigned short* __restrict__ qcl,
                         unsigned* __restrict__ cursor,
                         unsigned* __restrict__ entries_n, double* __restrict__ entries_w) {
    int lane = threadIdx.x & 63;
    unsigned gw = (blockIdx.x * blockDim.x + threadIdx.x) >> 6;
    unsigned nw = (gridDim.x * blockDim.x) >> 6;
    unsigned total = qcnt[0]; if (total > QCAP) total = QCAP;

    for (unsigned q = gw; q < total; q += nw) {
        unsigned rec = qn[q];
        int n = (int)(rec & 0xFFFFFFu);
        int cnt = (int)(rec >> 24);
        int sub = (n >> 5) & (NSUB - 1);       // == tile & 7
        const unsigned short* cl = qcl + (size_t)q * LCAND;

        if (cnt == 2) {
            do_refine<2>(x, Cf64, csqd, cl, n, cnt, lane, sub, cursor, entries_n, entries_w);
        } else if (cnt <= 4) {
            do_refine<4>(x, Cf64, csqd, cl, n, cnt, lane, sub, cursor, entries_n, entries_w);
        } else if (cnt <= 8) {
            do_refine<8>(x, Cf64, csqd, cl, n, cnt, lane, sub, cursor, entries_n, entries_w);
        } else {
            // rare fallback (cnt 9..16): serial-candidate path
            double xa = (double)x[(size_t)n * DIM + lane];
            double xb = (double)x[(size_t)n * DIM + 64 + lane];
            double myd = 1e300; int myk = -1;
            for (int c = 0; c < cnt; ++c) {
                int k = (int)cl[c];
                double pr = xa * Cf64[(size_t)k * DIM + lane]
                          + xb * Cf64[(size_t)k * DIM + 64 + lane];
                #pragma unroll
                for (int m = 1; m < 64; m <<= 1) pr += __shfl_xor(pr, m);
                double dist = csqd[k] - 2.0 * pr;
                if (lane == c) { myd = dist; myk = k; }
            }
            double md = myd;
            #pragma unroll
            for (int m = 1; m < 64; m <<= 1) md = fmin(md, __shfl_xor(md, m));
            double zm = -md / BETA;
            double arg = (myk >= 0) ? (-myd / BETA - zm) : -1e300;
            double e = (myk >= 0) ? exp(arg) : 0.0;
            double esum = e;
            #pragma unroll
            for (int m = 1; m < 64; m <<= 1) esum += __shfl_xor(esum, m);
            if (myk >= 0 && arg >= ACUT) {
                double wgt = e / esum;
                size_t base = (size_t)myk * NSUB + sub;
                unsigned pos = atomicAdd(&cursor[base * CSTRIDE], 1u);
                if (pos < SUBCAP) {
                    entries_n[base * SUBCAP + pos] = (unsigned)n;
                    entries_w[base * SUBCAP + pos] = wgt;
                }
            }
        }
    }
}

// ---------------- k_reduce: gather per-center entries, partial f64 sums ----------------
// 2048 blocks = 4 partials per center (2 sub-buckets each); 128 threads (one per dim)
__global__ void k_reduce(const float* __restrict__ x, const unsigned* __restrict__ cursor,
                         const unsigned* __restrict__ entries_n,
                         const double* __restrict__ entries_w,
                         double* __restrict__ num, double* __restrict__ den) {
    int b = blockIdx.x;
    int k = b >> 2, part = b & 3;
    int d = threadIdx.x;

    double a0 = 0.0, a1 = 0.0, a2 = 0.0, a3 = 0.0, ws = 0.0;
    #pragma unroll
    for (int s = 0; s < 2; ++s) {
        int sub = part * 2 + s;
        size_t base = (size_t)k * NSUB + sub;
        unsigned len = cursor[base * CSTRIDE]; if (len > SUBCAP) len = SUBCAP;
        const unsigned* en = entries_n + base * SUBCAP;
        const double*   ew = entries_w + base * SUBCAP;
        unsigned e = 0;
        for (; e + 4 <= len; e += 4) {
            unsigned n0 = en[e], n1 = en[e + 1], n2 = en[e + 2], n3 = en[e + 3];
            double w0 = ew[e], w1 = ew[e + 1], w2 = ew[e + 2], w3 = ew[e + 3];
            float f0 = x[(size_t)n0 * DIM + d];
            float f1 = x[(size_t)n1 * DIM + d];
            float f2 = x[(size_t)n2 * DIM + d];
            float f3 = x[(size_t)n3 * DIM + d];
            a0 += w0 * (double)f0; a1 += w1 * (double)f1;
            a2 += w2 * (double)f2; a3 += w3 * (double)f3;
            ws += ((w0 + w1) + (w2 + w3));
        }
        for (; e < len; ++e) {
            unsigned n0 = en[e]; double w0 = ew[e];
            a0 += w0 * (double)x[(size_t)n0 * DIM + d];
            ws += w0;
        }
    }
    double acc = (a0 + a1) + (a2 + a3);
    atomicAdd(&num[(size_t)k * DIM + d], acc);
    if (d == 0) atomicAdd(&den[k], ws);
}

// ---------------- k_update: centers = num/(den+EPS); refresh; zero state ----------------
__global__ void k_update(double* __restrict__ num, double* __restrict__ den,
                         double* __restrict__ Cf64, unsigned short* __restrict__ Cfrag,
                         double* __restrict__ csqd, float* __restrict__ csqf,
                         unsigned* __restrict__ cursor, unsigned* __restrict__ qcnt,
                         float* __restrict__ out, int last) {
    int k = blockIdx.x, d = threadIdx.x;       // 512 blocks x 128 threads
    double nv = num[(size_t)k * DIM + d];
    double dv = den[k] + EPS;
    double c = nv / dv;
    Cf64[(size_t)k * DIM + d] = c;
    num[(size_t)k * DIM + d] = 0.0;
    if (d < NSUB) cursor[((size_t)k * NSUB + d) * CSTRIDE] = 0u;
    if (k == 0 && d == 0) qcnt[0] = 0u;
    if (last) out[k * DIM + d] = (float)c;
    int ct = k >> 5, kb = d >> 4, j = d & 15;
    int lane = (k & 31) + 32 * (j >> 3);
    Cfrag[(((size_t)ct * 8 + kb) * 64 + lane) * 8 + (j & 7)] = f2bf((float)c);
    double p = c * c;
    #pragma unroll
    for (int m = 1; m < 64; m <<= 1) p += __shfl_xor(p, m);
    __shared__ double ps[2];
    if ((d & 63) == 0) ps[d >> 6] = p;
    __syncthreads();
    if (d == 0) {
        double s = ps[0] + ps[1];
        csqd[k] = s; csqf[k] = (float)s;
        den[k] = 0.0;
    }
}

extern "C" void kernel_launch(void* const* d_in, const int* in_sizes, int n_in,
                              void* d_out, int out_size, void* d_ws, size_t ws_size,
                              hipStream_t stream) {
    const float* x   = (const float*)d_in[0];
    const float* cin = (const float*)d_in[1];
    float* out = (float*)d_out;

    char* w = (char*)d_ws;
    size_t off = 0;
    auto alloc = [&](size_t bytes) -> void* {
        void* p = w + off;
        off = (off + bytes + 255) & ~(size_t)255;
        return p;
    };
    double*         Cf64   = (double*)alloc((size_t)KC * DIM * 8);          // 512 KB
    unsigned short* Cfrag  = (unsigned short*)alloc((size_t)KC * DIM * 2);  // 128 KB
    double*         csqd   = (double*)alloc((size_t)KC * 8);
    float*          csqf   = (float*)alloc((size_t)KC * 4);
    double*         num    = (double*)alloc((size_t)KC * DIM * 8);          // 512 KB
    double*         den    = (double*)alloc((size_t)KC * 8);
    unsigned*       cursor = (unsigned*)alloc((size_t)KC * NSUB * CSTRIDE * 4);   // 256 KB
    unsigned*       entries_n = (unsigned*)alloc((size_t)KC * NSUB * SUBCAP * 4); // 8.4 MB
    double*         entries_w = (double*)alloc((size_t)KC * NSUB * SUBCAP * 8);   // 16.8 MB
    unsigned*       qcnt   = (unsigned*)alloc(256);
    unsigned*       qn     = (unsigned*)alloc((size_t)QCAP * 4);            // 512 KB
    unsigned short* qcl    = (unsigned short*)alloc((size_t)QCAP * LCAND * 2); // 4 MB
    short8*         Xf     = (short8*)alloc((size_t)N_PTS * DIM * 2);       // 51.2 MB
    (void)ws_size; (void)in_sizes; (void)n_in; (void)out_size;

    hipLaunchKernelGGL(k_init, dim3(KC), dim3(DIM), 0, stream,
                       cin, Cf64, Cfrag, csqd, csqf, num, den, cursor, qcnt);
    hipLaunchKernelGGL(k_packx, dim3(NTILE), dim3(256), 0, stream, x, Xf);

    for (int it = 0; it < NITER; ++it) {
        hipLaunchKernelGGL(k_dense, dim3(NTILE), dim3(512), 0, stream,
                           Xf, (const short8*)Cfrag, csqf,
                           cursor, entries_n, entries_w, qcnt, qn, qcl);
        hipLaunchKernelGGL(k_refine, dim3(2048), dim3(256), 0, stream,
                           x, Cf64, csqd, qcnt, qn, qcl,
                           cursor, entries_n, entries_w);
        hipLaunchKernelGGL(k_reduce, dim3(KC * 4), dim3(DIM), 0, stream,
                           x, cursor, entries_n, entries_w, num, den);
        hipLaunchKernelGGL(k_update, dim3(KC), dim3(DIM), 0, stream,
                           num, den, Cf64, Cfrag, csqd, csqf, cursor, qcnt, out,
                           (it == NITER - 1) ? 1 : 0);
    }
}